// Round 16
// baseline (172.497 us; speedup 1.0000x reference)
//
#include <hip/hip_runtime.h>
#include <hip/hip_bf16.h>
#include <stdint.h>

// Shapes (fixed): B=4, N=8, Q=256, K=1024, D_MODEL=512, H=8, Dh=64, R=8, sigma=0.05

typedef __attribute__((ext_vector_type(8))) short bf16x8;
typedef __attribute__((ext_vector_type(4))) float f32x4;

__device__ __forceinline__ unsigned short f2b(float f){
    unsigned int u = __builtin_bit_cast(unsigned int, f);
    unsigned int r = u + 0x7fffu + ((u >> 16) & 1u);   // RNE
    return (unsigned short)(r >> 16);
}
__device__ __forceinline__ float b2f(unsigned short h){
    unsigned int u = ((unsigned int)h) << 16;
    return __builtin_bit_cast(float, u);
}

// packed f32->bf16x2 (RNE), single HW instr
__device__ __forceinline__ unsigned cvtpk2(float lo, float hi){
    unsigned r;
    asm("v_cvt_pk_bf16_f32 %0, %1, %2" : "=v"(r) : "v"(lo), "v"(hi));
    return r;
}

// single-level XOR swizzle for 64-col bf16 LDS tiles (0 conflicts measured r2)
__device__ __forceinline__ int swz(int row, int byteInRow){
    return row*128 + (byteInRow ^ ((row & 7) << 4));
}

// direct-to-LDS async copy, 16B per lane
#define GLDS16(g, l) __builtin_amdgcn_global_load_lds( \
    (const __attribute__((address_space(1))) void*)(g), \
    (__attribute__((address_space(3))) void*)(l), 16, 0, 0)

// DPP butterflies within 16-lane row
template<int CTRL>
__device__ __forceinline__ float dpp_mov(float x){
    return __builtin_bit_cast(float,
        __builtin_amdgcn_update_dpp(0, __builtin_bit_cast(int, x), CTRL, 0xF, 0xF, true));
}
__device__ __forceinline__ float grp16_sum(float x){
    x += dpp_mov<0xB1>(x);
    x += dpp_mov<0x4E>(x);
    x += dpp_mov<0x141>(x);
    x += dpp_mov<0x140>(x);
    return x;
}

// ---------------- all 4 weight transposes in one launch ---------------------
__global__ __launch_bounds__(256) void wt4_kernel(
    const float* __restrict__ Wq, const float* __restrict__ Wk,
    const float* __restrict__ Wv, const float* __restrict__ Wo,
    unsigned short* __restrict__ WtBase){
    __shared__ float tile[64][65];
    int kt = blockIdx.x, nt = blockIdx.y, wsel = blockIdx.z;
    const float* W = (wsel == 0) ? Wq : (wsel == 1) ? Wk : (wsel == 2) ? Wv : Wo;
    unsigned short* Wt = WtBase + (size_t)wsel * 262144;
    int tid = threadIdx.x;
    #pragma unroll
    for(int it=0; it<16; ++it){
        int idx = it*256 + tid;
        int r = idx >> 6, c = idx & 63;
        tile[r][c] = W[(kt*64 + r)*512 + nt*64 + c];
    }
    __syncthreads();
    #pragma unroll
    for(int it=0; it<16; ++it){
        int idx = it*256 + tid;
        int r = idx >> 6, c = idx & 63;
        Wt[(nt*64 + r)*512 + kt*64 + c] = f2b(tile[c][r]);
    }
}

// ---------------- positional features -> augmented MFMA operands ------------
// FULL bias in base-2 = -200*L2E*dist^2 + lf  (<= lf, bounded above!)
//  Q: [qwh0,qwh0,qwl0, qwh1,qwh1,qwl1, qwh2,qwh2,qwl2, 1,1, cqh,cql, 0..]
//  K: [kxh, kxl, kxh,  kyh, kyl, kyh,  kzh, kzl, kzh,  n2h,n2l, 1,1, 0..]
__global__ __launch_bounds__(256) void posfeat2_kernel(
    const float* __restrict__ qpos, const float* __restrict__ kpos,
    const float* __restrict__ Wqb,  const float* __restrict__ Wkb,
    const int* __restrict__ mask,
    unsigned short* __restrict__ qaug,   // [1024][32] bf16
    unsigned short* __restrict__ kaug){  // [4096][32] bf16
    const float L2E = 1.4426950408889634f;
    const float S8  = 0.35355339059327373f;
    int id = blockIdx.x*256 + threadIdx.x;
    unsigned short o[32];
    #pragma unroll
    for(int i=0;i<32;++i) o[i] = 0;
    if(id < 1024){
        const float* p = qpos + id*3;
        float x = p[0], y = p[1], z = p[2];
        float qw[3] = {400.f*x, 400.f*y, 400.f*z};
        #pragma unroll
        for(int r=0;r<8;++r){
            float qb = x*Wqb[r] + y*Wqb[8+r] + z*Wqb[16+r];
            float c  = S8*qb;
            qw[0] += c*Wkb[r];
            qw[1] += c*Wkb[8+r];
            qw[2] += c*Wkb[16+r];
        }
        #pragma unroll
        for(int i=0;i<3;++i){
            float w = qw[i]*L2E;
            unsigned short h = f2b(w);
            unsigned short lo = f2b(w - b2f(h));
            o[i*3+0] = h; o[i*3+1] = h; o[i*3+2] = lo;
        }
        o[9] = f2b(1.0f); o[10] = f2b(1.0f);
        float cq = -200.0f*(x*x + y*y + z*z)*L2E;     // per-q constant (bounds logits)
        unsigned short ch = f2b(cq);
        o[11] = ch; o[12] = f2b(cq - b2f(ch));
        uint4* d = reinterpret_cast<uint4*>(qaug + (size_t)id*32);
        const uint4* s = reinterpret_cast<const uint4*>(o);
        d[0]=s[0]; d[1]=s[1]; d[2]=s[2]; d[3]=s[3];
    } else if(id < 5120){
        int k = id - 1024;
        const float* p = kpos + k*3;
        float c3[3] = {p[0], p[1], p[2]};
        float n2 = -200.0f*(c3[0]*c3[0] + c3[1]*c3[1] + c3[2]*c3[2])*L2E;
        if(!mask[k]) n2 = -50000.0f;
        #pragma unroll
        for(int i=0;i<3;++i){
            unsigned short h = f2b(c3[i]);
            unsigned short lo = f2b(c3[i] - b2f(h));
            o[i*3+0] = h; o[i*3+1] = lo; o[i*3+2] = h;
        }
        unsigned short nh = f2b(n2);
        o[9] = nh; o[10] = f2b(n2 - b2f(nh));
        o[11] = f2b(1.0f); o[12] = f2b(1.0f);
        uint4* d = reinterpret_cast<uint4*>(kaug + (size_t)k*32);
        const uint4* s = reinterpret_cast<const uint4*>(o);
        d[0]=s[0]; d[1]=s[1]; d[2]=s[2]; d[3]=s[3];
    }
}

// ---------------- f32 -> bf16 streaming convert (8 elems/thread) ------------
__global__ __launch_bounds__(256) void cvt_kernel(
    const float* __restrict__ in, unsigned short* __restrict__ out, int n8){
    for(int id = blockIdx.x*256 + threadIdx.x; id < n8; id += gridDim.x*256){
        const float4* ip = reinterpret_cast<const float4*>(in) + (size_t)id*2;
        float4 a = ip[0], b = ip[1];
        uint4 w;
        w.x = cvtpk2(a.x, a.y); w.y = cvtpk2(a.z, a.w);
        w.z = cvtpk2(b.x, b.y); w.w = cvtpk2(b.z, b.w);
        reinterpret_cast<uint4*>(out)[id] = w;
    }
}

// ---------------- GEMM bf16-A (m97 structure), EPI 0=bf16 1=f32 out ---------
template<int EPI>
__global__ __launch_bounds__(256, 4) void gemm512g(
    const unsigned short* __restrict__ A,
    const unsigned short* __restrict__ Bt,
    const float* __restrict__ bias,
    void* __restrict__ Cv, float oscale){
    __shared__ alignas(16) char sm[32768];
    char* As = sm;
    char* Bs = sm + 16384;

    int nwg = gridDim.x;
    int q8  = nwg >> 3;
    int bid = blockIdx.x;
    int wgid = (bid & 7)*q8 + (bid >> 3);    // XCD-chunked bijection
    int n0 = (wgid & 3)*128, m0 = (wgid >> 2)*128;

    int tid = threadIdx.x;
    int l = tid & 63, wid = tid >> 6;
    int wr = wid >> 1, wc = wid & 1;
    int l15 = l & 15, lg = l >> 4;

    int srow8 = l >> 3;
    int scolb = ((l & 7) ^ srow8) << 4;

    f32x4 acc[4][4];
    const f32x4 z4 = {0.f,0.f,0.f,0.f};
    #pragma unroll
    for(int m=0;m<4;++m)
        #pragma unroll
        for(int n=0;n<4;++n) acc[m][n] = z4;

    for(int kt=0; kt<8; ++kt){
        int k0 = kt*64;
        __syncthreads();
        #pragma unroll
        for(int i=0;i<4;++i){
            int row = wid*32 + i*8 + srow8;
            const char* asrc = (const char*)(A  + (size_t)(m0+row)*512 + k0) + scolb;
            const char* bsrc = (const char*)(Bt + (size_t)(n0+row)*512 + k0) + scolb;
            GLDS16(asrc, As + wid*4096 + i*1024);
            GLDS16(bsrc, Bs + wid*4096 + i*1024);
        }
        __syncthreads();
        #pragma unroll
        for(int kk=0; kk<2; ++kk){
            bf16x8 af[4], bfr[4];
            #pragma unroll
            for(int m=0;m<4;++m)
                af[m] = *reinterpret_cast<const bf16x8*>(As + swz(wr*64 + m*16 + l15, kk*64 + lg*16));
            #pragma unroll
            for(int n=0;n<4;++n)
                bfr[n] = *reinterpret_cast<const bf16x8*>(Bs + swz(wc*64 + n*16 + l15, kk*64 + lg*16));
            #pragma unroll
            for(int m=0;m<4;++m)
                #pragma unroll
                for(int n=0;n<4;++n)
                    acc[m][n] = __builtin_amdgcn_mfma_f32_16x16x32_bf16(af[m], bfr[n], acc[m][n], 0, 0, 0);
        }
    }

    #pragma unroll
    for(int m=0;m<4;++m){
        int row = m0 + wr*64 + m*16 + lg*4;
        #pragma unroll
        for(int n=0;n<4;++n){
            int col = n0 + wc*64 + n*16 + l15;
            float bv = bias[col];
            #pragma unroll
            for(int j=0;j<4;++j){
                float val = (acc[m][n][j] + bv) * oscale;
                if(EPI == 0)
                    reinterpret_cast<unsigned short*>(Cv)[(size_t)(row+j)*512 + col] = f2b(val);
                else
                    reinterpret_cast<float*>(Cv)[(size_t)(row+j)*512 + col] = val;
            }
        }
    }
}

// ---------------- merged K|V projection, 256x128 tiles, 8 waves -------------
__global__ __launch_bounds__(512, 4) void gemm_kv3(
    const unsigned short* __restrict__ A,      // [16384][512] bf16 (chunk)
    const unsigned short* __restrict__ BtKV,   // [1024][512] bf16
    const float* __restrict__ bk_, const float* __restrict__ bv_,
    unsigned short* __restrict__ kp,           // chunk base
    unsigned short* __restrict__ vpT){         // chunk base
    __shared__ alignas(16) char sm[49152];
    char* As = sm;            // 256 rows x 128B (swz), 32KB
    char* Bs = sm + 32768;    // 128 rows x 128B (swz), 16KB

    int nwg = gridDim.x;                     // 512
    int q8  = nwg >> 3;
    int bid = blockIdx.x;
    int wgid = (bid & 7)*q8 + (bid >> 3);    // XCD-chunked bijection
    int n0 = (wgid & 7)*128, m0 = (wgid >> 3)*256;

    int tid = threadIdx.x;
    int l = tid & 63, wid = tid >> 6;        // wid 0..7
    int wr = wid >> 1, wc = wid & 1;
    int l15 = l & 15, lg = l >> 4;

    int r8 = l >> 3;
    int scolb = ((l & 7) ^ r8) << 4;

    f32x4 acc[4][4];
    const f32x4 z4 = {0.f,0.f,0.f,0.f};
    #pragma unroll
    for(int m=0;m<4;++m)
        #pragma unroll
        for(int n=0;n<4;++n) acc[m][n] = z4;

    for(int kt=0; kt<8; ++kt){
        int k0 = kt*64;
        __syncthreads();
        #pragma unroll
        for(int i=0;i<4;++i){
            int row = wid*32 + i*8 + r8;
            const char* asrc = (const char*)(A + (size_t)(m0+row)*512 + k0) + scolb;
            GLDS16(asrc, As + wid*4096 + i*1024);
        }
        #pragma unroll
        for(int i=0;i<2;++i){
            int row = wid*16 + i*8 + r8;
            const char* bsrc = (const char*)(BtKV + (size_t)(n0+row)*512 + k0) + scolb;
            GLDS16(bsrc, Bs + wid*2048 + i*1024);
        }
        __syncthreads();
        #pragma unroll
        for(int kk=0; kk<2; ++kk){
            bf16x8 af[4], bfr[4];
            #pragma unroll
            for(int m=0;m<4;++m)
                af[m] = *reinterpret_cast<const bf16x8*>(As + swz(wr*64 + m*16 + l15, kk*64 + lg*16));
            #pragma unroll
            for(int n=0;n<4;++n)
                bfr[n] = *reinterpret_cast<const bf16x8*>(Bs + swz(wc*64 + n*16 + l15, kk*64 + lg*16));
            #pragma unroll
            for(int m=0;m<4;++m)
                #pragma unroll
                for(int n=0;n<4;++n)
                    acc[m][n] = __builtin_amdgcn_mfma_f32_16x16x32_bf16(af[m], bfr[n], acc[m][n], 0, 0, 0);
        }
    }

    if(n0 < 512){
        #pragma unroll
        for(int m=0;m<4;++m){
            int row = m0 + wr*64 + m*16 + lg*4;
            #pragma unroll
            for(int n=0;n<4;++n){
                int col = n0 + wc*64 + n*16 + l15;
                float bv = bk_[col];
                #pragma unroll
                for(int j=0;j<4;++j)
                    kp[(size_t)(row+j)*512 + col] = f2b(acc[m][n][j] + bv);
            }
        }
    } else {
        int z = m0 >> 10;                    // chunk-local z (0..15)
        #pragma unroll
        for(int m=0;m<4;++m){
            int kloc = (m0 & 1023) + wr*64 + m*16 + lg*4;
            #pragma unroll
            for(int n=0;n<4;++n){
                int col = n0 - 512 + wc*64 + n*16 + l15;   // h*64+d
                float bv = bv_[col];
                int vrow = (z*8 + (col >> 6))*64 + (col & 63);
                uint2 w;
                w.x = cvtpk2(acc[m][n][0] + bv, acc[m][n][1] + bv);
                w.y = cvtpk2(acc[m][n][2] + bv, acc[m][n][3] + bv);
                *reinterpret_cast<uint2*>(vpT + (size_t)vrow*1024 + kloc) = w;
            }
        }
    }
}

// ---------------- attention v11: static softmax, V direct from L2 -----------
// 512 blocks x 512 threads; wave = 16 q-rows. K+aug LDS-dbuf (GLDS staged);
// V fragments read straight from global vpT into registers (VMEM pipe),
// issued early so L2 latency hides under the QK MFMA+LDS phase.
// Cuts LDS reads/wave-tile 22->14 b128 (attn9 was ~80% LDS-pipe-bound).
__global__ __launch_bounds__(512) void attn11_kernel(
    const unsigned short* __restrict__ qp,   // [8192][512] bf16, pre-scaled
    const unsigned short* __restrict__ kp,   // [32768][512] bf16
    const unsigned short* __restrict__ vpT,  // [(z*8+h)*64+d][1024] bf16
    const unsigned short* __restrict__ qaug, // [1024][32] bf16
    const unsigned short* __restrict__ kaug, // [4096][32] bf16
    unsigned short* __restrict__ ctxb){      // [8192][512] bf16
    __shared__ alignas(16) char sm[40960];
    char* KsA = sm;              // [64 k][64 d] swz, 8KB
    char* KsB = sm + 8192;
    char* FsA = sm + 16384;      // [64 k][32 feat] slot-swz, 4KB
    char* FsB = sm + 20480;
    char* Ps  = sm + 24576;      // 8 waves x 2KB

    int bid = blockIdx.x;
    int xcd = bid & 7, idx = bid >> 3;
    int zh = xcd*32 + (idx >> 1), qs = idx & 1;
    int z = zh >> 3, h = zh & 7;
    int b = z >> 3;
    int tid = threadIdx.x, l = tid & 63, wid = tid >> 6;
    int l15 = l & 15, lg = l >> 4;

    const unsigned short* kbase = kp  + (size_t)(z*1024)*512 + h*64;
    const unsigned short* vbase = vpT + (size_t)((z*8+h)*64)*1024;
    char* Pw = Ps + wid*2048;
    int qbase = z*256 + qs*128 + wid*16;

    // staging source addresses (pre-swizzled; linear LDS dest per rule #21)
    int r8 = tid >> 3;
    int csrc = ((tid & 7) ^ (r8 & 7)) << 4;
    const char* kSrc = (const char*)kbase + (size_t)r8*1024 + csrc;
    // kaug: threads 0..255 cover 64 rows x 4 slots with slot-XOR pre-swizzle
    int fk = (tid & 255) >> 2, fslot = tid & 3;
    const char* fSrc = (const char*)(kaug + (size_t)(b*1024 + fk)*32)
                       + ((fslot ^ ((fk >> 1) & 3)) << 4);

    // Q fragments (16 q-rows) + aug A-fragment, held for all tiles
    bf16x8 qf[2];
    #pragma unroll
    for(int kk=0;kk<2;++kk)
        qf[kk] = *reinterpret_cast<const bf16x8*>(
            qp + (size_t)(qbase + l15)*512 + h*64 + kk*32 + lg*8);
    bf16x8 qfa = *reinterpret_cast<const bf16x8*>(
        qaug + (size_t)(b*256 + qs*128 + wid*16 + l15)*32 + lg*8);

    f32x4 psum;
    f32x4 acc[4];
    const f32x4 z4 = {0.f,0.f,0.f,0.f};
    psum = z4;
    #pragma unroll
    for(int t=0;t<4;++t) acc[t] = z4;

    auto stage = [&](int kt, char* Ks, char* Fs){
        GLDS16(kSrc + (size_t)kt*65536, Ks + wid*1024);   // K: 64 rows x 1024B
        if(wid < 4) GLDS16(fSrc + (size_t)kt*4096, Fs + wid*1024);
    };

    auto body = [&](int kt, const char* Ks, const char* Fs){
        // V fragments issued first: L2 latency hides under QK phase
        bf16x8 vf[4][2];
        #pragma unroll
        for(int t=0;t<4;++t)
            #pragma unroll
            for(int kk=0;kk<2;++kk)
                vf[t][kk] = *reinterpret_cast<const bf16x8*>(
                    vbase + (size_t)(t*16 + l15)*1024 + kt*64 + kk*32 + lg*8);

        // S = Q@K^T + bias (aug chunk), all in MFMA, base-2 domain
        f32x4 s[4];
        #pragma unroll
        for(int t=0;t<4;++t){
            bf16x8 kfa = *reinterpret_cast<const bf16x8*>(
                Fs + (t*16 + l15)*64 + ((lg ^ ((l15 >> 1) & 3)) << 4));
            s[t] = __builtin_amdgcn_mfma_f32_16x16x32_bf16(qfa, kfa, z4, 0, 0, 0);
        }
        __builtin_amdgcn_s_setprio(1);
        #pragma unroll
        for(int kk=0;kk<2;++kk){
            bf16x8 kf[4];
            #pragma unroll
            for(int t=0;t<4;++t)
                kf[t] = *reinterpret_cast<const bf16x8*>(Ks + swz(t*16 + l15, kk*64 + lg*16));
            #pragma unroll
            for(int t=0;t<4;++t)
                s[t] = __builtin_amdgcn_mfma_f32_16x16x32_bf16(qf[kk], kf[t], s[t], 0, 0, 0);
        }
        __builtin_amdgcn_s_setprio(0);

        // P = exp2(s) (static softmax; logits bounded), pack, per-wave LDS
        #pragma unroll
        for(int t=0;t<4;++t){
            float p0 = exp2f(s[t][0]);
            float p1 = exp2f(s[t][1]);
            float p2 = exp2f(s[t][2]);
            float p3 = exp2f(s[t][3]);
            psum += (f32x4){p0, p1, p2, p3};
            unsigned w01 = cvtpk2(p0, p1);
            unsigned w23 = cvtpk2(p2, p3);
            int cb = (t*16 + l15)*2;
            int row0 = lg*4;
            *reinterpret_cast<unsigned short*>(Pw + swz(row0+0, cb)) = (unsigned short)w01;
            *reinterpret_cast<unsigned short*>(Pw + swz(row0+1, cb)) = (unsigned short)(w01 >> 16);
            *reinterpret_cast<unsigned short*>(Pw + swz(row0+2, cb)) = (unsigned short)w23;
            *reinterpret_cast<unsigned short*>(Pw + swz(row0+3, cb)) = (unsigned short)(w23 >> 16);
        }
        // PV (P wave-local; lgkmcnt orders ds_write->ds_read); V from regs
        #pragma unroll
        for(int kk=0;kk<2;++kk){
            bf16x8 pa = *reinterpret_cast<const bf16x8*>(Pw + swz(l15, kk*64 + lg*16));
            __builtin_amdgcn_s_setprio(1);
            #pragma unroll
            for(int t=0;t<4;++t)
                acc[t] = __builtin_amdgcn_mfma_f32_16x16x32_bf16(pa, vf[t][kk], acc[t], 0, 0, 0);
            __builtin_amdgcn_s_setprio(0);
        }
    };

    // 2-phase dbuf: stage(kt+1) issued before compute(kt); 1 barrier/tile.
    stage(0, KsA, FsA);
    #pragma unroll 1
    for(int kt=0; kt<16; kt+=2){
        __syncthreads();
        stage(kt+1, KsB, FsB);
        body(kt, KsA, FsA);
        __syncthreads();
        if(kt < 14) stage(kt+2, KsA, FsA);
        body(kt+1, KsB, FsB);
    }

    // final row sums, normalize, write bf16 ctx
    float rl[4];
    #pragma unroll
    for(int j=0;j<4;++j) rl[j] = 1.0f / grp16_sum(psum[j]);
    #pragma unroll
    for(int j=0;j<4;++j){
        int row = qbase + lg*4 + j;
        #pragma unroll
        for(int t=0;t<4;++t)
            ctxb[(size_t)row*512 + h*64 + t*16 + l15] = f2b(acc[t][j] * rl[j]);
    }
}

// ---------------------------------------------------------------------------
extern "C" void kernel_launch(void* const* d_in, const int* in_sizes, int n_in,
                              void* d_out, int out_size, void* d_ws, size_t ws_size,
                              hipStream_t stream){
    (void)in_sizes; (void)n_in; (void)out_size; (void)ws_size;
    const float* query     = (const float*)d_in[0];
    const float* key_value = (const float*)d_in[1];
    const float* query_pos = (const float*)d_in[2];
    const float* key_pos   = (const float*)d_in[3];
    const int*   key_mask  = (const int*)d_in[4];
    const float* Wq  = (const float*)d_in[5];
    const float* bq  = (const float*)d_in[6];
    const float* Wk  = (const float*)d_in[7];
    const float* bk  = (const float*)d_in[8];
    const float* Wv  = (const float*)d_in[9];
    const float* bv  = (const float*)d_in[10];
    const float* Wo  = (const float*)d_in[11];
    const float* bo  = (const float*)d_in[12];
    const float* Wqb = (const float*)d_in[13];
    const float* Wkb = (const float*)d_in[14];

    const float SCALE2 = 0.18033688011112042f;   // 0.125 * log2(e)

    char* ws = (char*)d_ws;
    const size_t MB = 1048576;
    unsigned short* kp    = (unsigned short*)(ws);            // 32MB
    unsigned short* vpT   = (unsigned short*)(ws + 32*MB);    // 32MB
    unsigned short* qp    = (unsigned short*)(ws + 64*MB);    //  8MB
    unsigned short* kvb   = (unsigned short*)(ws + 72*MB);    // 16MB chunk buf
    unsigned short* ctxb  = (unsigned short*)(ws + 72*MB);    //  8MB (after kvb dies)
    unsigned short* WtQ   = (unsigned short*)(ws + 88*MB);    // Q | K | V | O
    unsigned short* WtK   = WtQ + 262144;                     // K,V contiguous
    unsigned short* WtO   = WtQ + 3*262144;
    unsigned short* qaug  = (unsigned short*)(ws + 90*MB);    // 64KB
    unsigned short* kaug  = (unsigned short*)(ws + 90*MB + 65536);  // 256KB
    unsigned short* qb    = (unsigned short*)d_out;           // dead before O-proj

    wt4_kernel<<<dim3(8,8,4), 256, 0, stream>>>(Wq, Wk, Wv, Wo, WtQ);
    posfeat2_kernel<<<20, 256, 0, stream>>>(query_pos, key_pos, Wqb, Wkb, key_mask, qaug, kaug);

    // Q path: convert + project (SCALE2 folded into output)
    cvt_kernel<<<2048, 256, 0, stream>>>(query, qb, 524288);
    gemm512g<0><<<256, 256, 0, stream>>>(qb, WtQ, bq, qp, SCALE2);

    // K/V path, 2 chunks of 16384 rows; one merged K|V GEMM per chunk
    for(int c=0; c<2; ++c){
        const float* kvc = key_value + (size_t)c*16384*512;
        cvt_kernel<<<2048, 256, 0, stream>>>(kvc, kvb, 1048576);
        gemm_kv3<<<512, 512, 0, stream>>>(kvb, WtK, bk, bv,
                                          kp + (size_t)c*16384*512,
                                          vpT + (size_t)c*8388608);
    }

    attn11_kernel<<<512, 512, 0, stream>>>(qp, kp, vpT, qaug, kaug, ctxb);

    gemm512g<1><<<256, 256, 0, stream>>>(ctxb, WtO, bo, d_out, 1.0f);
}

// Round 18
// 134.007 us; speedup vs baseline: 1.2872x; 1.2872x over previous
//
#include <hip/hip_runtime.h>
#include <hip/hip_bf16.h>
#include <stdint.h>

// Shapes (fixed): B=4, N=8, Q=256, K=1024, D_MODEL=512, H=8, Dh=64, R=8, sigma=0.05

typedef __attribute__((ext_vector_type(8))) short bf16x8;
typedef __attribute__((ext_vector_type(4))) float f32x4;

__device__ __forceinline__ unsigned short f2b(float f){
    unsigned int u = __builtin_bit_cast(unsigned int, f);
    unsigned int r = u + 0x7fffu + ((u >> 16) & 1u);   // RNE
    return (unsigned short)(r >> 16);
}
__device__ __forceinline__ float b2f(unsigned short h){
    unsigned int u = ((unsigned int)h) << 16;
    return __builtin_bit_cast(float, u);
}

// packed f32->bf16x2 (RNE), single HW instr
__device__ __forceinline__ unsigned cvtpk2(float lo, float hi){
    unsigned r;
    asm("v_cvt_pk_bf16_f32 %0, %1, %2" : "=v"(r) : "v"(lo), "v"(hi));
    return r;
}

// single-level XOR swizzle for 64-col bf16 LDS tiles (0 conflicts measured r2)
__device__ __forceinline__ int swz(int row, int byteInRow){
    return row*128 + (byteInRow ^ ((row & 7) << 4));
}

// direct-to-LDS async copy, 16B per lane
#define GLDS16(g, l) __builtin_amdgcn_global_load_lds( \
    (const __attribute__((address_space(1))) void*)(g), \
    (__attribute__((address_space(3))) void*)(l), 16, 0, 0)

// DPP butterflies within 16-lane row
template<int CTRL>
__device__ __forceinline__ float dpp_mov(float x){
    return __builtin_bit_cast(float,
        __builtin_amdgcn_update_dpp(0, __builtin_bit_cast(int, x), CTRL, 0xF, 0xF, true));
}
__device__ __forceinline__ float grp16_sum(float x){
    x += dpp_mov<0xB1>(x);
    x += dpp_mov<0x4E>(x);
    x += dpp_mov<0x141>(x);
    x += dpp_mov<0x140>(x);
    return x;
}

// ---------------- all 4 weight transposes in one launch ---------------------
__global__ __launch_bounds__(256) void wt4_kernel(
    const float* __restrict__ Wq, const float* __restrict__ Wk,
    const float* __restrict__ Wv, const float* __restrict__ Wo,
    unsigned short* __restrict__ WtBase){
    __shared__ float tile[64][65];
    int kt = blockIdx.x, nt = blockIdx.y, wsel = blockIdx.z;
    const float* W = (wsel == 0) ? Wq : (wsel == 1) ? Wk : (wsel == 2) ? Wv : Wo;
    unsigned short* Wt = WtBase + (size_t)wsel * 262144;
    int tid = threadIdx.x;
    #pragma unroll
    for(int it=0; it<16; ++it){
        int idx = it*256 + tid;
        int r = idx >> 6, c = idx & 63;
        tile[r][c] = W[(kt*64 + r)*512 + nt*64 + c];
    }
    __syncthreads();
    #pragma unroll
    for(int it=0; it<16; ++it){
        int idx = it*256 + tid;
        int r = idx >> 6, c = idx & 63;
        Wt[(nt*64 + r)*512 + kt*64 + c] = f2b(tile[c][r]);
    }
}

// ---------------- positional features -> augmented MFMA operands ------------
// FULL bias in base-2 = -200*L2E*dist^2 + lf  (<= lf, bounded above!)
//  Q: [qwh0,qwh0,qwl0, qwh1,qwh1,qwl1, qwh2,qwh2,qwl2, 1,1, cqh,cql, 0..]
//  K: [kxh, kxl, kxh,  kyh, kyl, kyh,  kzh, kzl, kzh,  n2h,n2l, 1,1, 0..]
__global__ __launch_bounds__(256) void posfeat2_kernel(
    const float* __restrict__ qpos, const float* __restrict__ kpos,
    const float* __restrict__ Wqb,  const float* __restrict__ Wkb,
    const int* __restrict__ mask,
    unsigned short* __restrict__ qaug,   // [1024][32] bf16
    unsigned short* __restrict__ kaug){  // [4096][32] bf16
    const float L2E = 1.4426950408889634f;
    const float S8  = 0.35355339059327373f;
    int id = blockIdx.x*256 + threadIdx.x;
    unsigned short o[32];
    #pragma unroll
    for(int i=0;i<32;++i) o[i] = 0;
    if(id < 1024){
        const float* p = qpos + id*3;
        float x = p[0], y = p[1], z = p[2];
        float qw[3] = {400.f*x, 400.f*y, 400.f*z};
        #pragma unroll
        for(int r=0;r<8;++r){
            float qb = x*Wqb[r] + y*Wqb[8+r] + z*Wqb[16+r];
            float c  = S8*qb;
            qw[0] += c*Wkb[r];
            qw[1] += c*Wkb[8+r];
            qw[2] += c*Wkb[16+r];
        }
        #pragma unroll
        for(int i=0;i<3;++i){
            float w = qw[i]*L2E;
            unsigned short h = f2b(w);
            unsigned short lo = f2b(w - b2f(h));
            o[i*3+0] = h; o[i*3+1] = h; o[i*3+2] = lo;
        }
        o[9] = f2b(1.0f); o[10] = f2b(1.0f);
        float cq = -200.0f*(x*x + y*y + z*z)*L2E;     // per-q constant (bounds logits)
        unsigned short ch = f2b(cq);
        o[11] = ch; o[12] = f2b(cq - b2f(ch));
        uint4* d = reinterpret_cast<uint4*>(qaug + (size_t)id*32);
        const uint4* s = reinterpret_cast<const uint4*>(o);
        d[0]=s[0]; d[1]=s[1]; d[2]=s[2]; d[3]=s[3];
    } else if(id < 5120){
        int k = id - 1024;
        const float* p = kpos + k*3;
        float c3[3] = {p[0], p[1], p[2]};
        float n2 = -200.0f*(c3[0]*c3[0] + c3[1]*c3[1] + c3[2]*c3[2])*L2E;
        if(!mask[k]) n2 = -50000.0f;
        #pragma unroll
        for(int i=0;i<3;++i){
            unsigned short h = f2b(c3[i]);
            unsigned short lo = f2b(c3[i] - b2f(h));
            o[i*3+0] = h; o[i*3+1] = lo; o[i*3+2] = h;
        }
        unsigned short nh = f2b(n2);
        o[9] = nh; o[10] = f2b(n2 - b2f(nh));
        o[11] = f2b(1.0f); o[12] = f2b(1.0f);
        uint4* d = reinterpret_cast<uint4*>(kaug + (size_t)k*32);
        const uint4* s = reinterpret_cast<const uint4*>(o);
        d[0]=s[0]; d[1]=s[1]; d[2]=s[2]; d[3]=s[3];
    }
}

// ---------------- f32 -> bf16 streaming convert (8 elems/thread) ------------
__global__ __launch_bounds__(256) void cvt_kernel(
    const float* __restrict__ in, unsigned short* __restrict__ out, int n8){
    for(int id = blockIdx.x*256 + threadIdx.x; id < n8; id += gridDim.x*256){
        const float4* ip = reinterpret_cast<const float4*>(in) + (size_t)id*2;
        float4 a = ip[0], b = ip[1];
        uint4 w;
        w.x = cvtpk2(a.x, a.y); w.y = cvtpk2(a.z, a.w);
        w.z = cvtpk2(b.x, b.y); w.w = cvtpk2(b.z, b.w);
        reinterpret_cast<uint4*>(out)[id] = w;
    }
}

// ---------------- GEMM bf16-A (m97 structure), EPI 0=bf16 1=f32 out ---------
template<int EPI>
__global__ __launch_bounds__(256, 4) void gemm512g(
    const unsigned short* __restrict__ A,
    const unsigned short* __restrict__ Bt,
    const float* __restrict__ bias,
    void* __restrict__ Cv, float oscale){
    __shared__ alignas(16) char sm[32768];
    char* As = sm;
    char* Bs = sm + 16384;

    int nwg = gridDim.x;
    int q8  = nwg >> 3;
    int bid = blockIdx.x;
    int wgid = (bid & 7)*q8 + (bid >> 3);    // XCD-chunked bijection
    int n0 = (wgid & 3)*128, m0 = (wgid >> 2)*128;

    int tid = threadIdx.x;
    int l = tid & 63, wid = tid >> 6;
    int wr = wid >> 1, wc = wid & 1;
    int l15 = l & 15, lg = l >> 4;

    int srow8 = l >> 3;
    int scolb = ((l & 7) ^ srow8) << 4;

    f32x4 acc[4][4];
    const f32x4 z4 = {0.f,0.f,0.f,0.f};
    #pragma unroll
    for(int m=0;m<4;++m)
        #pragma unroll
        for(int n=0;n<4;++n) acc[m][n] = z4;

    for(int kt=0; kt<8; ++kt){
        int k0 = kt*64;
        __syncthreads();
        #pragma unroll
        for(int i=0;i<4;++i){
            int row = wid*32 + i*8 + srow8;
            const char* asrc = (const char*)(A  + (size_t)(m0+row)*512 + k0) + scolb;
            const char* bsrc = (const char*)(Bt + (size_t)(n0+row)*512 + k0) + scolb;
            GLDS16(asrc, As + wid*4096 + i*1024);
            GLDS16(bsrc, Bs + wid*4096 + i*1024);
        }
        __syncthreads();
        #pragma unroll
        for(int kk=0; kk<2; ++kk){
            bf16x8 af[4], bfr[4];
            #pragma unroll
            for(int m=0;m<4;++m)
                af[m] = *reinterpret_cast<const bf16x8*>(As + swz(wr*64 + m*16 + l15, kk*64 + lg*16));
            #pragma unroll
            for(int n=0;n<4;++n)
                bfr[n] = *reinterpret_cast<const bf16x8*>(Bs + swz(wc*64 + n*16 + l15, kk*64 + lg*16));
            #pragma unroll
            for(int m=0;m<4;++m)
                #pragma unroll
                for(int n=0;n<4;++n)
                    acc[m][n] = __builtin_amdgcn_mfma_f32_16x16x32_bf16(af[m], bfr[n], acc[m][n], 0, 0, 0);
        }
    }

    #pragma unroll
    for(int m=0;m<4;++m){
        int row = m0 + wr*64 + m*16 + lg*4;
        #pragma unroll
        for(int n=0;n<4;++n){
            int col = n0 + wc*64 + n*16 + l15;
            float bv = bias[col];
            #pragma unroll
            for(int j=0;j<4;++j){
                float val = (acc[m][n][j] + bv) * oscale;
                if(EPI == 0)
                    reinterpret_cast<unsigned short*>(Cv)[(size_t)(row+j)*512 + col] = f2b(val);
                else
                    reinterpret_cast<float*>(Cv)[(size_t)(row+j)*512 + col] = val;
            }
        }
    }
}

// ---------------- merged K|V projection, 256x128 tiles, 8 waves -------------
// grid = 8 * m_tiles; z = m0>>10 relative to the A base (caller offsets bases).
__global__ __launch_bounds__(512, 4) void gemm_kv3(
    const unsigned short* __restrict__ A,      // [M][512] bf16
    const unsigned short* __restrict__ BtKV,   // [1024][512] bf16
    const float* __restrict__ bk_, const float* __restrict__ bv_,
    unsigned short* __restrict__ kp,
    unsigned short* __restrict__ vpT){
    __shared__ alignas(16) char sm[49152];
    char* As = sm;            // 256 rows x 128B (swz), 32KB
    char* Bs = sm + 32768;    // 128 rows x 128B (swz), 16KB

    int nwg = gridDim.x;
    int q8  = nwg >> 3;
    int bid = blockIdx.x;
    int wgid = (bid & 7)*q8 + (bid >> 3);    // XCD-chunked bijection
    int n0 = (wgid & 7)*128, m0 = (wgid >> 3)*256;

    int tid = threadIdx.x;
    int l = tid & 63, wid = tid >> 6;        // wid 0..7
    int wr = wid >> 1, wc = wid & 1;
    int l15 = l & 15, lg = l >> 4;

    int r8 = l >> 3;
    int scolb = ((l & 7) ^ r8) << 4;

    f32x4 acc[4][4];
    const f32x4 z4 = {0.f,0.f,0.f,0.f};
    #pragma unroll
    for(int m=0;m<4;++m)
        #pragma unroll
        for(int n=0;n<4;++n) acc[m][n] = z4;

    for(int kt=0; kt<8; ++kt){
        int k0 = kt*64;
        __syncthreads();
        #pragma unroll
        for(int i=0;i<4;++i){
            int row = wid*32 + i*8 + r8;
            const char* asrc = (const char*)(A + (size_t)(m0+row)*512 + k0) + scolb;
            GLDS16(asrc, As + wid*4096 + i*1024);
        }
        #pragma unroll
        for(int i=0;i<2;++i){
            int row = wid*16 + i*8 + r8;
            const char* bsrc = (const char*)(BtKV + (size_t)(n0+row)*512 + k0) + scolb;
            GLDS16(bsrc, Bs + wid*2048 + i*1024);
        }
        __syncthreads();
        #pragma unroll
        for(int kk=0; kk<2; ++kk){
            bf16x8 af[4], bfr[4];
            #pragma unroll
            for(int m=0;m<4;++m)
                af[m] = *reinterpret_cast<const bf16x8*>(As + swz(wr*64 + m*16 + l15, kk*64 + lg*16));
            #pragma unroll
            for(int n=0;n<4;++n)
                bfr[n] = *reinterpret_cast<const bf16x8*>(Bs + swz(wc*64 + n*16 + l15, kk*64 + lg*16));
            #pragma unroll
            for(int m=0;m<4;++m)
                #pragma unroll
                for(int n=0;n<4;++n)
                    acc[m][n] = __builtin_amdgcn_mfma_f32_16x16x32_bf16(af[m], bfr[n], acc[m][n], 0, 0, 0);
        }
    }

    if(n0 < 512){
        #pragma unroll
        for(int m=0;m<4;++m){
            int row = m0 + wr*64 + m*16 + lg*4;
            #pragma unroll
            for(int n=0;n<4;++n){
                int col = n0 + wc*64 + n*16 + l15;
                float bv = bk_[col];
                #pragma unroll
                for(int j=0;j<4;++j)
                    kp[(size_t)(row+j)*512 + col] = f2b(acc[m][n][j] + bv);
            }
        }
    } else {
        int z = m0 >> 10;
        #pragma unroll
        for(int m=0;m<4;++m){
            int kloc = (m0 & 1023) + wr*64 + m*16 + lg*4;
            #pragma unroll
            for(int n=0;n<4;++n){
                int col = n0 - 512 + wc*64 + n*16 + l15;   // h*64+d
                float bv = bv_[col];
                int vrow = (z*8 + (col >> 6))*64 + (col & 63);
                uint2 w;
                w.x = cvtpk2(acc[m][n][0] + bv, acc[m][n][1] + bv);
                w.y = cvtpk2(acc[m][n][2] + bv, acc[m][n][3] + bv);
                *reinterpret_cast<uint2*>(vpT + (size_t)vrow*1024 + kloc) = w;
            }
        }
    }
}

// ---------------- attention v9: static softmax + MFMA-fused bias ------------
// 512 blocks x 512 threads; wave = 16 q-rows; LDS-dbuf staging. (champion)
__global__ __launch_bounds__(512) void attn9_kernel(
    const unsigned short* __restrict__ qp,   // [8192][512] bf16, pre-scaled
    const unsigned short* __restrict__ kp,   // [32768][512] bf16
    const unsigned short* __restrict__ vpT,  // [(z*8+h)*64+d][1024] bf16
    const unsigned short* __restrict__ qaug, // [1024][32] bf16
    const unsigned short* __restrict__ kaug, // [4096][32] bf16
    unsigned short* __restrict__ ctxb){      // [8192][512] bf16
    __shared__ alignas(16) char sm[57344];
    char* KsA = sm;              // [64 k][64 d] swz, 8KB
    char* KsB = sm + 8192;
    char* VsA = sm + 16384;      // [64 d][64 k] swz, 8KB
    char* VsB = sm + 24576;
    char* FsA = sm + 32768;      // [64 k][32 feat] slot-swz, 4KB
    char* FsB = sm + 36864;
    char* Ps  = sm + 40960;      // 8 waves x 2KB

    int bid = blockIdx.x;
    int xcd = bid & 7, idx = bid >> 3;
    int zh = xcd*32 + (idx >> 1), qs = idx & 1;
    int z = zh >> 3, h = zh & 7;
    int b = z >> 3;
    int tid = threadIdx.x, l = tid & 63, wid = tid >> 6;
    int l15 = l & 15, lg = l >> 4;

    const unsigned short* kbase = kp  + (size_t)(z*1024)*512 + h*64;
    const unsigned short* vbase = vpT + (size_t)((z*8+h)*64)*1024;
    char* Pw = Ps + wid*2048;
    int qbase = z*256 + qs*128 + wid*16;

    // staging source addresses (pre-swizzled; linear LDS dest per rule #21)
    int r8 = tid >> 3;
    int csrc = ((tid & 7) ^ (r8 & 7)) << 4;
    const char* kSrc = (const char*)kbase + (size_t)r8*1024 + csrc;
    const char* vSrc = (const char*)vbase + (size_t)r8*2048 + csrc;
    // kaug: threads 0..255 cover 64 rows x 4 slots with slot-XOR pre-swizzle
    int fk = (tid & 255) >> 2, fslot = tid & 3;
    const char* fSrc = (const char*)(kaug + (size_t)(b*1024 + fk)*32)
                       + ((fslot ^ ((fk >> 1) & 3)) << 4);

    // Q fragments (16 q-rows) + aug A-fragment, held for all tiles
    bf16x8 qf[2];
    #pragma unroll
    for(int kk=0;kk<2;++kk)
        qf[kk] = *reinterpret_cast<const bf16x8*>(
            qp + (size_t)(qbase + l15)*512 + h*64 + kk*32 + lg*8);
    bf16x8 qfa = *reinterpret_cast<const bf16x8*>(
        qaug + (size_t)(b*256 + qs*128 + wid*16 + l15)*32 + lg*8);

    f32x4 psum;
    f32x4 acc[4];
    const f32x4 z4 = {0.f,0.f,0.f,0.f};
    psum = z4;
    #pragma unroll
    for(int t=0;t<4;++t) acc[t] = z4;

    auto stage = [&](int kt, char* Ks, char* Vs, char* Fs){
        GLDS16(kSrc + (size_t)kt*65536, Ks + wid*1024);   // K: 64 rows x 1024B
        GLDS16(vSrc + (size_t)kt*128,   Vs + wid*1024);   // V^T: 128B col walk
        if(wid < 4) GLDS16(fSrc + (size_t)kt*4096, Fs + wid*1024);
    };

    auto body = [&](int kt, const char* Ks, const char* Vs, const char* Fs){
        // S = Q@K^T + bias (aug chunk), all in MFMA, base-2 domain
        f32x4 s[4];
        #pragma unroll
        for(int t=0;t<4;++t){
            bf16x8 kfa = *reinterpret_cast<const bf16x8*>(
                Fs + (t*16 + l15)*64 + ((lg ^ ((l15 >> 1) & 3)) << 4));
            s[t] = __builtin_amdgcn_mfma_f32_16x16x32_bf16(qfa, kfa, z4, 0, 0, 0);
        }
        __builtin_amdgcn_s_setprio(1);
        #pragma unroll
        for(int kk=0;kk<2;++kk){
            bf16x8 kf[4];
            #pragma unroll
            for(int t=0;t<4;++t)
                kf[t] = *reinterpret_cast<const bf16x8*>(Ks + swz(t*16 + l15, kk*64 + lg*16));
            #pragma unroll
            for(int t=0;t<4;++t)
                s[t] = __builtin_amdgcn_mfma_f32_16x16x32_bf16(qf[kk], kf[t], s[t], 0, 0, 0);
        }
        __builtin_amdgcn_s_setprio(0);

        // P = exp2(s) (static softmax; logits bounded), pack, per-wave LDS
        #pragma unroll
        for(int t=0;t<4;++t){
            float p0 = exp2f(s[t][0]);
            float p1 = exp2f(s[t][1]);
            float p2 = exp2f(s[t][2]);
            float p3 = exp2f(s[t][3]);
            psum += (f32x4){p0, p1, p2, p3};
            unsigned w01 = cvtpk2(p0, p1);
            unsigned w23 = cvtpk2(p2, p3);
            int cb = (t*16 + l15)*2;
            int row0 = lg*4;
            *reinterpret_cast<unsigned short*>(Pw + swz(row0+0, cb)) = (unsigned short)w01;
            *reinterpret_cast<unsigned short*>(Pw + swz(row0+1, cb)) = (unsigned short)(w01 >> 16);
            *reinterpret_cast<unsigned short*>(Pw + swz(row0+2, cb)) = (unsigned short)w23;
            *reinterpret_cast<unsigned short*>(Pw + swz(row0+3, cb)) = (unsigned short)(w23 >> 16);
        }
        // PV (P wave-local; lgkmcnt orders ds_write->ds_read)
        #pragma unroll
        for(int kk=0;kk<2;++kk){
            bf16x8 vf[4];
            #pragma unroll
            for(int t=0;t<4;++t)
                vf[t] = *reinterpret_cast<const bf16x8*>(Vs + swz(t*16 + l15, kk*64 + lg*16));
            bf16x8 pa = *reinterpret_cast<const bf16x8*>(Pw + swz(l15, kk*64 + lg*16));
            __builtin_amdgcn_s_setprio(1);
            #pragma unroll
            for(int t=0;t<4;++t)
                acc[t] = __builtin_amdgcn_mfma_f32_16x16x32_bf16(pa, vf[t], acc[t], 0, 0, 0);
            __builtin_amdgcn_s_setprio(0);
        }
    };

    // 2-phase dbuf: stage(kt+1) issued before compute(kt); 1 barrier/tile.
    stage(0, KsA, VsA, FsA);
    #pragma unroll 1
    for(int kt=0; kt<16; kt+=2){
        __syncthreads();
        stage(kt+1, KsB, VsB, FsB);
        body(kt, KsA, VsA, FsA);
        __syncthreads();
        if(kt < 14) stage(kt+2, KsA, VsA, FsA);
        body(kt+1, KsB, VsB, FsB);
    }

    // final row sums, normalize, write bf16 ctx
    float rl[4];
    #pragma unroll
    for(int j=0;j<4;++j) rl[j] = 1.0f / grp16_sum(psum[j]);
    #pragma unroll
    for(int j=0;j<4;++j){
        int row = qbase + lg*4 + j;
        #pragma unroll
        for(int t=0;t<4;++t)
            ctxb[(size_t)row*512 + h*64 + t*16 + l15] = f2b(acc[t][j] * rl[j]);
    }
}

// ---------------------------------------------------------------------------
extern "C" void kernel_launch(void* const* d_in, const int* in_sizes, int n_in,
                              void* d_out, int out_size, void* d_ws, size_t ws_size,
                              hipStream_t stream){
    (void)in_sizes; (void)n_in; (void)out_size;
    const float* query     = (const float*)d_in[0];
    const float* key_value = (const float*)d_in[1];
    const float* query_pos = (const float*)d_in[2];
    const float* key_pos   = (const float*)d_in[3];
    const int*   key_mask  = (const int*)d_in[4];
    const float* Wq  = (const float*)d_in[5];
    const float* bq  = (const float*)d_in[6];
    const float* Wk  = (const float*)d_in[7];
    const float* bk  = (const float*)d_in[8];
    const float* Wv  = (const float*)d_in[9];
    const float* bv  = (const float*)d_in[10];
    const float* Wo  = (const float*)d_in[11];
    const float* bo  = (const float*)d_in[12];
    const float* Wqb = (const float*)d_in[13];
    const float* Wkb = (const float*)d_in[14];

    const float SCALE2 = 0.18033688011112042f;   // 0.125 * log2(e)

    char* ws = (char*)d_ws;
    const size_t MB = 1048576;
    unsigned short* kp    = (unsigned short*)(ws);            // 32MB
    unsigned short* vpT   = (unsigned short*)(ws + 32*MB);    // 32MB
    unsigned short* qp    = (unsigned short*)(ws + 64*MB);    //  8MB
    unsigned short* kvb   = (unsigned short*)(ws + 72*MB);    // 16MB (or 32MB big)
    unsigned short* ctxb  = (unsigned short*)(ws + 72*MB);    //  8MB (after kvb dies)

    // single-pass KV needs kvb = 32MB (ends at 104MB) + 2.4MB tail
    bool bigws = (ws_size >= 112*MB);
    size_t tail = bigws ? 104*MB : 88*MB;
    unsigned short* WtQ   = (unsigned short*)(ws + tail);     // Q | K | V | O
    unsigned short* WtK   = WtQ + 262144;                     // K,V contiguous
    unsigned short* WtO   = WtQ + 3*262144;
    unsigned short* qaug  = (unsigned short*)(ws + tail + 2*MB);
    unsigned short* kaug  = qaug + 32768;
    unsigned short* qb    = (unsigned short*)d_out;           // dead before O-proj

    wt4_kernel<<<dim3(8,8,4), 256, 0, stream>>>(Wq, Wk, Wv, Wo, WtQ);
    posfeat2_kernel<<<20, 256, 0, stream>>>(query_pos, key_pos, Wqb, Wkb, key_mask, qaug, kaug);

    // Q path: convert (4M f32 elems -> n8=524288) + project (SCALE2 folded)
    cvt_kernel<<<2048, 256, 0, stream>>>(query, qb, 524288);
    gemm512g<0><<<256, 256, 0, stream>>>(qb, WtQ, bq, qp, SCALE2);

    if(bigws){
        // single-pass K/V: 16.78M f32 elems -> n8 = 2097152 (16B uint4 units)
        cvt_kernel<<<2048, 256, 0, stream>>>(key_value, kvb, 2097152);
        gemm_kv3<<<1024, 512, 0, stream>>>(kvb, WtK, bk, bv, kp, vpT);
    } else {
        for(int c=0; c<2; ++c){
            const float* kvc = key_value + (size_t)c*16384*512;
            // 8.39M elems per chunk -> n8 = 1048576
            cvt_kernel<<<2048, 256, 0, stream>>>(kvc, kvb, 1048576);
            gemm_kv3<<<512, 512, 0, stream>>>(kvb, WtK, bk, bv,
                                              kp + (size_t)c*16384*512,
                                              vpT + (size_t)c*8388608);
        }
    }

    attn9_kernel<<<512, 512, 0, stream>>>(qp, kp, vpT, qaug, kaug, ctxb);

    gemm512g<1><<<256, 256, 0, stream>>>(ctxb, WtO, bo, d_out, 1.0f);
}

// Round 19
// 133.229 us; speedup vs baseline: 1.2947x; 1.0058x over previous
//
#include <hip/hip_runtime.h>
#include <hip/hip_bf16.h>
#include <stdint.h>

// Shapes (fixed): B=4, N=8, Q=256, K=1024, D_MODEL=512, H=8, Dh=64, R=8, sigma=0.05

typedef __attribute__((ext_vector_type(8))) short bf16x8;
typedef __attribute__((ext_vector_type(4))) float f32x4;

__device__ __forceinline__ unsigned short f2b(float f){
    unsigned int u = __builtin_bit_cast(unsigned int, f);
    unsigned int r = u + 0x7fffu + ((u >> 16) & 1u);   // RNE
    return (unsigned short)(r >> 16);
}
__device__ __forceinline__ float b2f(unsigned short h){
    unsigned int u = ((unsigned int)h) << 16;
    return __builtin_bit_cast(float, u);
}

// packed f32->bf16x2 (RNE), single HW instr
__device__ __forceinline__ unsigned cvtpk2(float lo, float hi){
    unsigned r;
    asm("v_cvt_pk_bf16_f32 %0, %1, %2" : "=v"(r) : "v"(lo), "v"(hi));
    return r;
}

// single-level XOR swizzle for 64-col bf16 LDS tiles (0 conflicts measured r2)
__device__ __forceinline__ int swz(int row, int byteInRow){
    return row*128 + (byteInRow ^ ((row & 7) << 4));
}

// direct-to-LDS async copy, 16B per lane
#define GLDS16(g, l) __builtin_amdgcn_global_load_lds( \
    (const __attribute__((address_space(1))) void*)(g), \
    (__attribute__((address_space(3))) void*)(l), 16, 0, 0)

// DPP butterflies within 16-lane row
template<int CTRL>
__device__ __forceinline__ float dpp_mov(float x){
    return __builtin_bit_cast(float,
        __builtin_amdgcn_update_dpp(0, __builtin_bit_cast(int, x), CTRL, 0xF, 0xF, true));
}
__device__ __forceinline__ float grp16_sum(float x){
    x += dpp_mov<0xB1>(x);
    x += dpp_mov<0x4E>(x);
    x += dpp_mov<0x141>(x);
    x += dpp_mov<0x140>(x);
    return x;
}

// ---------------- all 4 weight transposes in one launch ---------------------
__global__ __launch_bounds__(256) void wt4_kernel(
    const float* __restrict__ Wq, const float* __restrict__ Wk,
    const float* __restrict__ Wv, const float* __restrict__ Wo,
    unsigned short* __restrict__ WtBase){
    __shared__ float tile[64][65];
    int kt = blockIdx.x, nt = blockIdx.y, wsel = blockIdx.z;
    const float* W = (wsel == 0) ? Wq : (wsel == 1) ? Wk : (wsel == 2) ? Wv : Wo;
    unsigned short* Wt = WtBase + (size_t)wsel * 262144;
    int tid = threadIdx.x;
    #pragma unroll
    for(int it=0; it<16; ++it){
        int idx = it*256 + tid;
        int r = idx >> 6, c = idx & 63;
        tile[r][c] = W[(kt*64 + r)*512 + nt*64 + c];
    }
    __syncthreads();
    #pragma unroll
    for(int it=0; it<16; ++it){
        int idx = it*256 + tid;
        int r = idx >> 6, c = idx & 63;
        Wt[(nt*64 + r)*512 + kt*64 + c] = f2b(tile[c][r]);
    }
}

// ---------------- positional features -> augmented MFMA operands ------------
// FULL bias in base-2 = -200*L2E*dist^2 + lf  (<= lf, bounded above!)
//  Q: [qwh0,qwh0,qwl0, qwh1,qwh1,qwl1, qwh2,qwh2,qwl2, 1,1, cqh,cql, 0..]
//  K: [kxh, kxl, kxh,  kyh, kyl, kyh,  kzh, kzl, kzh,  n2h,n2l, 1,1, 0..]
__global__ __launch_bounds__(256) void posfeat2_kernel(
    const float* __restrict__ qpos, const float* __restrict__ kpos,
    const float* __restrict__ Wqb,  const float* __restrict__ Wkb,
    const int* __restrict__ mask,
    unsigned short* __restrict__ qaug,   // [1024][32] bf16
    unsigned short* __restrict__ kaug){  // [4096][32] bf16
    const float L2E = 1.4426950408889634f;
    const float S8  = 0.35355339059327373f;
    int id = blockIdx.x*256 + threadIdx.x;
    unsigned short o[32];
    #pragma unroll
    for(int i=0;i<32;++i) o[i] = 0;
    if(id < 1024){
        const float* p = qpos + id*3;
        float x = p[0], y = p[1], z = p[2];
        float qw[3] = {400.f*x, 400.f*y, 400.f*z};
        #pragma unroll
        for(int r=0;r<8;++r){
            float qb = x*Wqb[r] + y*Wqb[8+r] + z*Wqb[16+r];
            float c  = S8*qb;
            qw[0] += c*Wkb[r];
            qw[1] += c*Wkb[8+r];
            qw[2] += c*Wkb[16+r];
        }
        #pragma unroll
        for(int i=0;i<3;++i){
            float w = qw[i]*L2E;
            unsigned short h = f2b(w);
            unsigned short lo = f2b(w - b2f(h));
            o[i*3+0] = h; o[i*3+1] = h; o[i*3+2] = lo;
        }
        o[9] = f2b(1.0f); o[10] = f2b(1.0f);
        float cq = -200.0f*(x*x + y*y + z*z)*L2E;     // per-q constant (bounds logits)
        unsigned short ch = f2b(cq);
        o[11] = ch; o[12] = f2b(cq - b2f(ch));
        uint4* d = reinterpret_cast<uint4*>(qaug + (size_t)id*32);
        const uint4* s = reinterpret_cast<const uint4*>(o);
        d[0]=s[0]; d[1]=s[1]; d[2]=s[2]; d[3]=s[3];
    } else if(id < 5120){
        int k = id - 1024;
        const float* p = kpos + k*3;
        float c3[3] = {p[0], p[1], p[2]};
        float n2 = -200.0f*(c3[0]*c3[0] + c3[1]*c3[1] + c3[2]*c3[2])*L2E;
        if(!mask[k]) n2 = -50000.0f;
        #pragma unroll
        for(int i=0;i<3;++i){
            unsigned short h = f2b(c3[i]);
            unsigned short lo = f2b(c3[i] - b2f(h));
            o[i*3+0] = h; o[i*3+1] = lo; o[i*3+2] = h;
        }
        unsigned short nh = f2b(n2);
        o[9] = nh; o[10] = f2b(n2 - b2f(nh));
        o[11] = f2b(1.0f); o[12] = f2b(1.0f);
        uint4* d = reinterpret_cast<uint4*>(kaug + (size_t)k*32);
        const uint4* s = reinterpret_cast<const uint4*>(o);
        d[0]=s[0]; d[1]=s[1]; d[2]=s[2]; d[3]=s[3];
    }
}

// ---------------- f32 -> bf16 streaming convert (8 elems/thread) ------------
__global__ __launch_bounds__(256) void cvt_kernel(
    const float* __restrict__ in, unsigned short* __restrict__ out, int n8){
    for(int id = blockIdx.x*256 + threadIdx.x; id < n8; id += gridDim.x*256){
        const float4* ip = reinterpret_cast<const float4*>(in) + (size_t)id*2;
        float4 a = ip[0], b = ip[1];
        uint4 w;
        w.x = cvtpk2(a.x, a.y); w.y = cvtpk2(a.z, a.w);
        w.z = cvtpk2(b.x, b.y); w.w = cvtpk2(b.z, b.w);
        reinterpret_cast<uint4*>(out)[id] = w;
    }
}

// ---------------- fused dual-region convert (query + key_value) -------------
__global__ __launch_bounds__(256) void cvt2_kernel(
    const float* __restrict__ inq, unsigned short* __restrict__ outq, int nq8,
    const float* __restrict__ inkv, unsigned short* __restrict__ outkv, int nkv8){
    int total = nq8 + nkv8;
    for(int id = blockIdx.x*256 + threadIdx.x; id < total; id += gridDim.x*256){
        const float* in; unsigned short* out; int lid;
        if(id < nq8){ in = inq; out = outq; lid = id; }
        else        { in = inkv; out = outkv; lid = id - nq8; }
        const float4* ip = reinterpret_cast<const float4*>(in) + (size_t)lid*2;
        float4 a = ip[0], b = ip[1];
        uint4 w;
        w.x = cvtpk2(a.x, a.y); w.y = cvtpk2(a.z, a.w);
        w.z = cvtpk2(b.x, b.y); w.w = cvtpk2(b.z, b.w);
        reinterpret_cast<uint4*>(out)[lid] = w;
    }
}

// ---------------- GEMM bf16-A (m97 structure), EPI 0=bf16 1=f32 out ---------
template<int EPI>
__global__ __launch_bounds__(256, 4) void gemm512g(
    const unsigned short* __restrict__ A,
    const unsigned short* __restrict__ Bt,
    const float* __restrict__ bias,
    void* __restrict__ Cv, float oscale){
    __shared__ alignas(16) char sm[32768];
    char* As = sm;
    char* Bs = sm + 16384;

    int nwg = gridDim.x;
    int q8  = nwg >> 3;
    int bid = blockIdx.x;
    int wgid = (bid & 7)*q8 + (bid >> 3);    // XCD-chunked bijection
    int n0 = (wgid & 3)*128, m0 = (wgid >> 2)*128;

    int tid = threadIdx.x;
    int l = tid & 63, wid = tid >> 6;
    int wr = wid >> 1, wc = wid & 1;
    int l15 = l & 15, lg = l >> 4;

    int srow8 = l >> 3;
    int scolb = ((l & 7) ^ srow8) << 4;

    f32x4 acc[4][4];
    const f32x4 z4 = {0.f,0.f,0.f,0.f};
    #pragma unroll
    for(int m=0;m<4;++m)
        #pragma unroll
        for(int n=0;n<4;++n) acc[m][n] = z4;

    for(int kt=0; kt<8; ++kt){
        int k0 = kt*64;
        __syncthreads();
        #pragma unroll
        for(int i=0;i<4;++i){
            int row = wid*32 + i*8 + srow8;
            const char* asrc = (const char*)(A  + (size_t)(m0+row)*512 + k0) + scolb;
            const char* bsrc = (const char*)(Bt + (size_t)(n0+row)*512 + k0) + scolb;
            GLDS16(asrc, As + wid*4096 + i*1024);
            GLDS16(bsrc, Bs + wid*4096 + i*1024);
        }
        __syncthreads();
        #pragma unroll
        for(int kk=0; kk<2; ++kk){
            bf16x8 af[4], bfr[4];
            #pragma unroll
            for(int m=0;m<4;++m)
                af[m] = *reinterpret_cast<const bf16x8*>(As + swz(wr*64 + m*16 + l15, kk*64 + lg*16));
            #pragma unroll
            for(int n=0;n<4;++n)
                bfr[n] = *reinterpret_cast<const bf16x8*>(Bs + swz(wc*64 + n*16 + l15, kk*64 + lg*16));
            #pragma unroll
            for(int m=0;m<4;++m)
                #pragma unroll
                for(int n=0;n<4;++n)
                    acc[m][n] = __builtin_amdgcn_mfma_f32_16x16x32_bf16(af[m], bfr[n], acc[m][n], 0, 0, 0);
        }
    }

    #pragma unroll
    for(int m=0;m<4;++m){
        int row = m0 + wr*64 + m*16 + lg*4;
        #pragma unroll
        for(int n=0;n<4;++n){
            int col = n0 + wc*64 + n*16 + l15;
            float bv = bias[col];
            #pragma unroll
            for(int j=0;j<4;++j){
                float val = (acc[m][n][j] + bv) * oscale;
                if(EPI == 0)
                    reinterpret_cast<unsigned short*>(Cv)[(size_t)(row+j)*512 + col] = f2b(val);
                else
                    reinterpret_cast<float*>(Cv)[(size_t)(row+j)*512 + col] = val;
            }
        }
    }
}

// ---------------- merged K|V projection, 256x128 tiles, 8 waves -------------
// grid = 8 * m_tiles; z = m0>>10 relative to the A base (caller offsets bases).
__global__ __launch_bounds__(512, 4) void gemm_kv3(
    const unsigned short* __restrict__ A,      // [M][512] bf16
    const unsigned short* __restrict__ BtKV,   // [1024][512] bf16
    const float* __restrict__ bk_, const float* __restrict__ bv_,
    unsigned short* __restrict__ kp,
    unsigned short* __restrict__ vpT){
    __shared__ alignas(16) char sm[49152];
    char* As = sm;            // 256 rows x 128B (swz), 32KB
    char* Bs = sm + 32768;    // 128 rows x 128B (swz), 16KB

    int nwg = gridDim.x;
    int q8  = nwg >> 3;
    int bid = blockIdx.x;
    int wgid = (bid & 7)*q8 + (bid >> 3);    // XCD-chunked bijection
    int n0 = (wgid & 7)*128, m0 = (wgid >> 3)*256;

    int tid = threadIdx.x;
    int l = tid & 63, wid = tid >> 6;        // wid 0..7
    int wr = wid >> 1, wc = wid & 1;
    int l15 = l & 15, lg = l >> 4;

    int r8 = l >> 3;
    int scolb = ((l & 7) ^ r8) << 4;

    f32x4 acc[4][4];
    const f32x4 z4 = {0.f,0.f,0.f,0.f};
    #pragma unroll
    for(int m=0;m<4;++m)
        #pragma unroll
        for(int n=0;n<4;++n) acc[m][n] = z4;

    for(int kt=0; kt<8; ++kt){
        int k0 = kt*64;
        __syncthreads();
        #pragma unroll
        for(int i=0;i<4;++i){
            int row = wid*32 + i*8 + r8;
            const char* asrc = (const char*)(A + (size_t)(m0+row)*512 + k0) + scolb;
            GLDS16(asrc, As + wid*4096 + i*1024);
        }
        #pragma unroll
        for(int i=0;i<2;++i){
            int row = wid*16 + i*8 + r8;
            const char* bsrc = (const char*)(BtKV + (size_t)(n0+row)*512 + k0) + scolb;
            GLDS16(bsrc, Bs + wid*2048 + i*1024);
        }
        __syncthreads();
        #pragma unroll
        for(int kk=0; kk<2; ++kk){
            bf16x8 af[4], bfr[4];
            #pragma unroll
            for(int m=0;m<4;++m)
                af[m] = *reinterpret_cast<const bf16x8*>(As + swz(wr*64 + m*16 + l15, kk*64 + lg*16));
            #pragma unroll
            for(int n=0;n<4;++n)
                bfr[n] = *reinterpret_cast<const bf16x8*>(Bs + swz(wc*64 + n*16 + l15, kk*64 + lg*16));
            #pragma unroll
            for(int m=0;m<4;++m)
                #pragma unroll
                for(int n=0;n<4;++n)
                    acc[m][n] = __builtin_amdgcn_mfma_f32_16x16x32_bf16(af[m], bfr[n], acc[m][n], 0, 0, 0);
        }
    }

    if(n0 < 512){
        #pragma unroll
        for(int m=0;m<4;++m){
            int row = m0 + wr*64 + m*16 + lg*4;
            #pragma unroll
            for(int n=0;n<4;++n){
                int col = n0 + wc*64 + n*16 + l15;
                float bv = bk_[col];
                #pragma unroll
                for(int j=0;j<4;++j)
                    kp[(size_t)(row+j)*512 + col] = f2b(acc[m][n][j] + bv);
            }
        }
    } else {
        int z = m0 >> 10;
        #pragma unroll
        for(int m=0;m<4;++m){
            int kloc = (m0 & 1023) + wr*64 + m*16 + lg*4;
            #pragma unroll
            for(int n=0;n<4;++n){
                int col = n0 - 512 + wc*64 + n*16 + l15;   // h*64+d
                float bv = bv_[col];
                int vrow = (z*8 + (col >> 6))*64 + (col & 63);
                uint2 w;
                w.x = cvtpk2(acc[m][n][0] + bv, acc[m][n][1] + bv);
                w.y = cvtpk2(acc[m][n][2] + bv, acc[m][n][3] + bv);
                *reinterpret_cast<uint2*>(vpT + (size_t)vrow*1024 + kloc) = w;
            }
        }
    }
}

// ---------------- attention v9: static softmax + MFMA-fused bias ------------
// 512 blocks x 512 threads; wave = 16 q-rows; LDS-dbuf staging. (champion)
__global__ __launch_bounds__(512) void attn9_kernel(
    const unsigned short* __restrict__ qp,   // [8192][512] bf16, pre-scaled
    const unsigned short* __restrict__ kp,   // [32768][512] bf16
    const unsigned short* __restrict__ vpT,  // [(z*8+h)*64+d][1024] bf16
    const unsigned short* __restrict__ qaug, // [1024][32] bf16
    const unsigned short* __restrict__ kaug, // [4096][32] bf16
    unsigned short* __restrict__ ctxb){      // [8192][512] bf16
    __shared__ alignas(16) char sm[57344];
    char* KsA = sm;              // [64 k][64 d] swz, 8KB
    char* KsB = sm + 8192;
    char* VsA = sm + 16384;      // [64 d][64 k] swz, 8KB
    char* VsB = sm + 24576;
    char* FsA = sm + 32768;      // [64 k][32 feat] slot-swz, 4KB
    char* FsB = sm + 36864;
    char* Ps  = sm + 40960;      // 8 waves x 2KB

    int bid = blockIdx.x;
    int xcd = bid & 7, idx = bid >> 3;
    int zh = xcd*32 + (idx >> 1), qs = idx & 1;
    int z = zh >> 3, h = zh & 7;
    int b = z >> 3;
    int tid = threadIdx.x, l = tid & 63, wid = tid >> 6;
    int l15 = l & 15, lg = l >> 4;

    const unsigned short* kbase = kp  + (size_t)(z*1024)*512 + h*64;
    const unsigned short* vbase = vpT + (size_t)((z*8+h)*64)*1024;
    char* Pw = Ps + wid*2048;
    int qbase = z*256 + qs*128 + wid*16;

    // staging source addresses (pre-swizzled; linear LDS dest per rule #21)
    int r8 = tid >> 3;
    int csrc = ((tid & 7) ^ (r8 & 7)) << 4;
    const char* kSrc = (const char*)kbase + (size_t)r8*1024 + csrc;
    const char* vSrc = (const char*)vbase + (size_t)r8*2048 + csrc;
    // kaug: threads 0..255 cover 64 rows x 4 slots with slot-XOR pre-swizzle
    int fk = (tid & 255) >> 2, fslot = tid & 3;
    const char* fSrc = (const char*)(kaug + (size_t)(b*1024 + fk)*32)
                       + ((fslot ^ ((fk >> 1) & 3)) << 4);

    // Q fragments (16 q-rows) + aug A-fragment, held for all tiles
    bf16x8 qf[2];
    #pragma unroll
    for(int kk=0;kk<2;++kk)
        qf[kk] = *reinterpret_cast<const bf16x8*>(
            qp + (size_t)(qbase + l15)*512 + h*64 + kk*32 + lg*8);
    bf16x8 qfa = *reinterpret_cast<const bf16x8*>(
        qaug + (size_t)(b*256 + qs*128 + wid*16 + l15)*32 + lg*8);

    f32x4 psum;
    f32x4 acc[4];
    const f32x4 z4 = {0.f,0.f,0.f,0.f};
    psum = z4;
    #pragma unroll
    for(int t=0;t<4;++t) acc[t] = z4;

    auto stage = [&](int kt, char* Ks, char* Vs, char* Fs){
        GLDS16(kSrc + (size_t)kt*65536, Ks + wid*1024);   // K: 64 rows x 1024B
        GLDS16(vSrc + (size_t)kt*128,   Vs + wid*1024);   // V^T: 128B col walk
        if(wid < 4) GLDS16(fSrc + (size_t)kt*4096, Fs + wid*1024);
    };

    auto body = [&](int kt, const char* Ks, const char* Vs, const char* Fs){
        // S = Q@K^T + bias (aug chunk), all in MFMA, base-2 domain
        f32x4 s[4];
        #pragma unroll
        for(int t=0;t<4;++t){
            bf16x8 kfa = *reinterpret_cast<const bf16x8*>(
                Fs + (t*16 + l15)*64 + ((lg ^ ((l15 >> 1) & 3)) << 4));
            s[t] = __builtin_amdgcn_mfma_f32_16x16x32_bf16(qfa, kfa, z4, 0, 0, 0);
        }
        __builtin_amdgcn_s_setprio(1);
        #pragma unroll
        for(int kk=0;kk<2;++kk){
            bf16x8 kf[4];
            #pragma unroll
            for(int t=0;t<4;++t)
                kf[t] = *reinterpret_cast<const bf16x8*>(Ks + swz(t*16 + l15, kk*64 + lg*16));
            #pragma unroll
            for(int t=0;t<4;++t)
                s[t] = __builtin_amdgcn_mfma_f32_16x16x32_bf16(qf[kk], kf[t], s[t], 0, 0, 0);
        }
        __builtin_amdgcn_s_setprio(0);

        // P = exp2(s) (static softmax; logits bounded), pack, per-wave LDS
        #pragma unroll
        for(int t=0;t<4;++t){
            float p0 = exp2f(s[t][0]);
            float p1 = exp2f(s[t][1]);
            float p2 = exp2f(s[t][2]);
            float p3 = exp2f(s[t][3]);
            psum += (f32x4){p0, p1, p2, p3};
            unsigned w01 = cvtpk2(p0, p1);
            unsigned w23 = cvtpk2(p2, p3);
            int cb = (t*16 + l15)*2;
            int row0 = lg*4;
            *reinterpret_cast<unsigned short*>(Pw + swz(row0+0, cb)) = (unsigned short)w01;
            *reinterpret_cast<unsigned short*>(Pw + swz(row0+1, cb)) = (unsigned short)(w01 >> 16);
            *reinterpret_cast<unsigned short*>(Pw + swz(row0+2, cb)) = (unsigned short)w23;
            *reinterpret_cast<unsigned short*>(Pw + swz(row0+3, cb)) = (unsigned short)(w23 >> 16);
        }
        // PV (P wave-local; lgkmcnt orders ds_write->ds_read)
        #pragma unroll
        for(int kk=0;kk<2;++kk){
            bf16x8 vf[4];
            #pragma unroll
            for(int t=0;t<4;++t)
                vf[t] = *reinterpret_cast<const bf16x8*>(Vs + swz(t*16 + l15, kk*64 + lg*16));
            bf16x8 pa = *reinterpret_cast<const bf16x8*>(Pw + swz(l15, kk*64 + lg*16));
            __builtin_amdgcn_s_setprio(1);
            #pragma unroll
            for(int t=0;t<4;++t)
                acc[t] = __builtin_amdgcn_mfma_f32_16x16x32_bf16(pa, vf[t], acc[t], 0, 0, 0);
            __builtin_amdgcn_s_setprio(0);
        }
    };

    // 2-phase dbuf: stage(kt+1) issued before compute(kt); 1 barrier/tile.
    stage(0, KsA, VsA, FsA);
    #pragma unroll 1
    for(int kt=0; kt<16; kt+=2){
        __syncthreads();
        stage(kt+1, KsB, VsB, FsB);
        body(kt, KsA, VsA, FsA);
        __syncthreads();
        if(kt < 14) stage(kt+2, KsA, VsA, FsA);
        body(kt+1, KsB, VsB, FsB);
    }

    // final row sums, normalize, write bf16 ctx
    float rl[4];
    #pragma unroll
    for(int j=0;j<4;++j) rl[j] = 1.0f / grp16_sum(psum[j]);
    #pragma unroll
    for(int j=0;j<4;++j){
        int row = qbase + lg*4 + j;
        #pragma unroll
        for(int t=0;t<4;++t)
            ctxb[(size_t)row*512 + h*64 + t*16 + l15] = f2b(acc[t][j] * rl[j]);
    }
}

// ---------------------------------------------------------------------------
extern "C" void kernel_launch(void* const* d_in, const int* in_sizes, int n_in,
                              void* d_out, int out_size, void* d_ws, size_t ws_size,
                              hipStream_t stream){
    (void)in_sizes; (void)n_in; (void)out_size;
    const float* query     = (const float*)d_in[0];
    const float* key_value = (const float*)d_in[1];
    const float* query_pos = (const float*)d_in[2];
    const float* key_pos   = (const float*)d_in[3];
    const int*   key_mask  = (const int*)d_in[4];
    const float* Wq  = (const float*)d_in[5];
    const float* bq  = (const float*)d_in[6];
    const float* Wk  = (const float*)d_in[7];
    const float* bk  = (const float*)d_in[8];
    const float* Wv  = (const float*)d_in[9];
    const float* bv  = (const float*)d_in[10];
    const float* Wo  = (const float*)d_in[11];
    const float* bo  = (const float*)d_in[12];
    const float* Wqb = (const float*)d_in[13];
    const float* Wkb = (const float*)d_in[14];

    const float SCALE2 = 0.18033688011112042f;   // 0.125 * log2(e)

    char* ws = (char*)d_ws;
    const size_t MB = 1048576;
    unsigned short* kp    = (unsigned short*)(ws);            // 32MB
    unsigned short* vpT   = (unsigned short*)(ws + 32*MB);    // 32MB
    unsigned short* qp    = (unsigned short*)(ws + 64*MB);    //  8MB
    unsigned short* kvb   = (unsigned short*)(ws + 72*MB);    // 16MB (or 32MB big)
    unsigned short* ctxb  = (unsigned short*)(ws + 72*MB);    //  8MB (after kvb dies)

    // single-pass KV needs kvb = 32MB (ends at 104MB) + 2.4MB tail
    bool bigws = (ws_size >= 112*MB);
    size_t tail = bigws ? 104*MB : 88*MB;
    unsigned short* WtQ   = (unsigned short*)(ws + tail);     // Q | K | V | O
    unsigned short* WtK   = WtQ + 262144;                     // K,V contiguous
    unsigned short* WtO   = WtQ + 3*262144;
    unsigned short* qaug  = (unsigned short*)(ws + tail + 2*MB);
    unsigned short* kaug  = qaug + 32768;
    unsigned short* qb    = (unsigned short*)d_out;           // dead before O-proj

    wt4_kernel<<<dim3(8,8,4), 256, 0, stream>>>(Wq, Wk, Wv, Wo, WtQ);
    posfeat2_kernel<<<20, 256, 0, stream>>>(query_pos, key_pos, Wqb, Wkb, key_mask, qaug, kaug);

    if(bigws){
        // one fused convert: query (n8=524288) + key_value (n8=2097152)
        cvt2_kernel<<<2048, 256, 0, stream>>>(query, qb, 524288,
                                              key_value, kvb, 2097152);
        gemm512g<0><<<256, 256, 0, stream>>>(qb, WtQ, bq, qp, SCALE2);
        gemm_kv3<<<1024, 512, 0, stream>>>(kvb, WtK, bk, bv, kp, vpT);
    } else {
        cvt_kernel<<<2048, 256, 0, stream>>>(query, qb, 524288);
        gemm512g<0><<<256, 256, 0, stream>>>(qb, WtQ, bq, qp, SCALE2);
        for(int c=0; c<2; ++c){
            const float* kvc = key_value + (size_t)c*16384*512;
            cvt_kernel<<<2048, 256, 0, stream>>>(kvc, kvb, 1048576);
            gemm_kv3<<<512, 512, 0, stream>>>(kvb, WtK, bk, bv,
                                              kp + (size_t)c*16384*512,
                                              vpT + (size_t)c*8388608);
        }
    }

    attn9_kernel<<<512, 512, 0, stream>>>(qp, kp, vpT, qaug, kaug, ctxb);

    gemm512g<1><<<256, 256, 0, stream>>>(ctxb, WtO, bo, d_out, 1.0f);
}